// Round 9
// baseline (997.778 us; speedup 1.0000x reference)
//
#include <hip/hip_runtime.h>

#define EPSf 1e-5f

// Hand-rolled bf16 (round-to-nearest-even) for ws intermediates.
static __device__ __forceinline__ unsigned short f32_to_bf16(float f) {
    unsigned int u = __float_as_uint(f);
    unsigned int r = (u + 0x7FFFu + ((u >> 16) & 1u)) >> 16;
    return (unsigned short)r;
}
static __device__ __forceinline__ float bf16_to_f32(unsigned short h) {
    return __uint_as_float(((unsigned int)h) << 16);
}

// 3x3 conv (pad=1) + BN + ReLU, BN folded inline from raw params.
// Tile: 16x8 pixels, 32 of 64 c_out per block. grid = (12, 24, B*2), block = 128.
__global__ __launch_bounds__(128) void conv3x3_bn_relu(
    const float* __restrict__ in,    // [B,64,192,192] f32
    const float* __restrict__ wgt,   // [64,64,3,3]
    const float* __restrict__ bias,  // [64]
    const float* __restrict__ bn_g, const float* __restrict__ bn_be,
    const float* __restrict__ bn_m, const float* __restrict__ bn_v,
    unsigned short* __restrict__ out)  // [B,64,192,192] bf16 bits (workspace)
{
    __shared__ float tile[180];      // 10 rows x 18 cols
    const int t  = threadIdx.x;
    const int tx = t & 15, ty = t >> 4;
    const int x0 = blockIdx.x << 4, y0 = blockIdx.y << 3;
    const int hf = blockIdx.z & 1, b = blockIdx.z >> 1;
    const int x = x0 + tx, y = y0 + ty;
    const int cobase = hf << 5;

    float acc[32];
#pragma unroll
    for (int i = 0; i < 32; ++i) acc[i] = 0.f;

    const int r0 = t / 18, q0 = t - r0 * 18;
    const int t1 = t + 128;
    const int r1 = t1 / 18, q1 = t1 - r1 * 18;
    const int gy0 = y0 - 1 + r0, gx0 = x0 - 1 + q0;
    const int gy1 = y0 - 1 + r1, gx1 = x0 - 1 + q1;
    const bool ok0 = (gy0 >= 0 && gy0 < 192 && gx0 >= 0 && gx0 < 192);
    const bool ok1 = (t1 < 180) && (gy1 >= 0 && gy1 < 192 && gx1 >= 0 && gx1 < 192);
    const float* inb = in + (size_t)b * 64 * 36864;

    for (int ci = 0; ci < 64; ++ci) {
        const float* inc = inb + (size_t)ci * 36864;
        tile[t] = ok0 ? inc[gy0 * 192 + gx0] : 0.f;
        if (t1 < 180) tile[t1] = ok1 ? inc[gy1 * 192 + gx1] : 0.f;
        __syncthreads();

        float v[9];
#pragma unroll
        for (int i = 0; i < 3; ++i)
#pragma unroll
            for (int j = 0; j < 3; ++j)
                v[i * 3 + j] = tile[(ty + i) * 18 + tx + j];

        const float* wp = wgt + ((size_t)cobase * 64 + ci) * 9;
#pragma unroll
        for (int co = 0; co < 32; ++co)
#pragma unroll
            for (int k = 0; k < 9; ++k)
                acc[co] = fmaf(wp[co * 576 + k], v[k], acc[co]);
        __syncthreads();
    }

    size_t ob = (size_t)b * 64 * 36864 + (size_t)y * 192 + x;
#pragma unroll
    for (int co = 0; co < 32; ++co) {
        int c = cobase + co;
        float inv = bn_g[c] / sqrtf(bn_v[c] + EPSf);
        float sh  = (bias[c] - bn_m[c]) * inv + bn_be[c];
        float r = fmaf(acc[co], inv, sh);
        out[ob + (size_t)c * 36864] = f32_to_bf16(r > 0.f ? r : 0.f);
    }
}

// Fused: local correlation (R=4, 81 shifts) + concat + 1x1 conv (145->64) + BN + ReLU.
// corr channel = dx*9+dy, value = 0.125 * sum_c f1[c,y,x] * f2[c, y+dy-4, x+dx-4]
// grid = (12, 24, B), block = 128. OUTPUT IS FLOAT32.
__global__ __launch_bounds__(128) void corr_conv1x1_bn_relu(
    const unsigned short* __restrict__ f1, const unsigned short* __restrict__ f2,
    const float* __restrict__ qw,    // [64][145]
    const float* __restrict__ qb,
    const float* __restrict__ qg, const float* __restrict__ qbe,
    const float* __restrict__ qm, const float* __restrict__ qv,
    float* __restrict__ out)         // [B,64,192,192] f32
{
    __shared__ float sf2[3072];      // 8 ch x 16 rows x 24 cols
    const int t  = threadIdx.x;
    const int tx = t & 15, ty = t >> 4;
    const int x0 = blockIdx.x << 4, y0 = blockIdx.y << 3;
    const int b = blockIdx.z;
    const int x = x0 + tx, y = y0 + ty;
    const unsigned short* f1b = f1 + (size_t)b * 64 * 36864;
    const unsigned short* f2b = f2 + (size_t)b * 64 * 36864;

    float corr[81];
#pragma unroll
    for (int i = 0; i < 81; ++i) corr[i] = 0.f;

    for (int c0 = 0; c0 < 64; c0 += 8) {
        // stage 8 channels of the 16x24 f2 window (zero-padded at borders)
#pragma unroll
        for (int k = 0; k < 24; ++k) {
            int i = t + (k << 7);
            int cc = i / 384; int rem = i - cc * 384;
            int r = rem / 24; int col = rem - r * 24;
            int gy = y0 - 4 + r, gx = x0 - 4 + col;
            float vv = 0.f;
            if (gy >= 0 && gy < 192 && gx >= 0 && gx < 192)
                vv = bf16_to_f32(f2b[(size_t)(c0 + cc) * 36864 + gy * 192 + gx]);
            sf2[i] = vv;
        }
        __syncthreads();

#pragma unroll
        for (int cc = 0; cc < 8; ++cc) {
            float f1v = bf16_to_f32(f1b[(size_t)(c0 + cc) * 36864 + y * 192 + x]);
            const float* sp = &sf2[cc * 384 + ty * 24 + tx];
#pragma unroll
            for (int dy = 0; dy < 9; ++dy)
#pragma unroll
                for (int dx = 0; dx < 9; ++dx)
                    corr[dx * 9 + dy] = fmaf(f1v, sp[dy * 24 + dx], corr[dx * 9 + dy]);
        }
        __syncthreads();
    }

#pragma unroll
    for (int d = 0; d < 81; ++d) corr[d] *= 0.125f;   // 1/sqrt(64)

    float f1r[64];
#pragma unroll
    for (int c = 0; c < 64; ++c)
        f1r[c] = bf16_to_f32(f1b[(size_t)c * 36864 + y * 192 + x]);

    size_t ob = (size_t)b * 64 * 36864 + (size_t)y * 192 + x;
    for (int co = 0; co < 64; ++co) {
        const float* wp = qw + co * 145;
        float a0 = 0.f, a1 = 0.f, a2 = 0.f, a3 = 0.f;
#pragma unroll
        for (int d = 0; d < 80; d += 4) {
            a0 = fmaf(wp[d + 0], corr[d + 0], a0);
            a1 = fmaf(wp[d + 1], corr[d + 1], a1);
            a2 = fmaf(wp[d + 2], corr[d + 2], a2);
            a3 = fmaf(wp[d + 3], corr[d + 3], a3);
        }
        a0 = fmaf(wp[80], corr[80], a0);
#pragma unroll
        for (int c = 0; c < 64; c += 4) {
            a0 = fmaf(wp[81 + c + 0], f1r[c + 0], a0);
            a1 = fmaf(wp[81 + c + 1], f1r[c + 1], a1);
            a2 = fmaf(wp[81 + c + 2], f1r[c + 2], a2);
            a3 = fmaf(wp[81 + c + 3], f1r[c + 3], a3);
        }
        float acc = (a0 + a1) + (a2 + a3);
        float inv = qg[co] / sqrtf(qv[co] + EPSf);
        float sh  = (qb[co] - qm[co]) * inv + qbe[co];
        float r = fmaf(acc, inv, sh);
        out[ob + (size_t)co * 36864] = (r > 0.f ? r : 0.f);   // f32 store
    }
}

extern "C" void kernel_launch(void* const* d_in, const int* in_sizes, int n_in,
                              void* d_out, int out_size, void* d_ws, size_t ws_size,
                              hipStream_t stream) {
    float* out = (float*)d_out;   // reference output dtype is float32

    // ws: f1 | f2, each 4*64*192*192 bf16 = 18.87 MB (total 37.75 MB)
    unsigned short* f1 = (unsigned short*)d_ws;
    unsigned short* f2 = f1 + (size_t)4 * 64 * 36864;

    dim3 cgrid(12, 24, 8);
    conv3x3_bn_relu<<<cgrid, 128, 0, stream>>>(
        (const float*)d_in[0], (const float*)d_in[2], (const float*)d_in[3],
        (const float*)d_in[4], (const float*)d_in[5], (const float*)d_in[6],
        (const float*)d_in[7], f1);
    conv3x3_bn_relu<<<cgrid, 128, 0, stream>>>(
        (const float*)d_in[1], (const float*)d_in[8], (const float*)d_in[9],
        (const float*)d_in[10], (const float*)d_in[11], (const float*)d_in[12],
        (const float*)d_in[13], f2);

    dim3 ggrid(12, 24, 4);
    corr_conv1x1_bn_relu<<<ggrid, 128, 0, stream>>>(
        f1, f2,
        (const float*)d_in[14], (const float*)d_in[15], (const float*)d_in[16],
        (const float*)d_in[17], (const float*)d_in[18], (const float*)d_in[19],
        out);
}